// Round 1
// baseline (10007.677 us; speedup 1.0000x reference)
//
#include <hip/hip_runtime.h>

// ---------------------------------------------------------------------------
// 2-layer LSTM (B=2048, T=64, I=128, H=1024) + per-step fc, MI355X/gfx950.
// Strategy: fp16 MFMA (16x16x32) GEMMs in the m97 128x128-tile structure with
// fused gate activations in the epilogue (gate-interleaved N tiling so each
// lane owns all 4 gates of one (row,unit)). fp32 accumulate + fp32 c-state.
// ---------------------------------------------------------------------------

typedef _Float16 f16x8 __attribute__((ext_vector_type(8)));
typedef _Float16 f16x4 __attribute__((ext_vector_type(4)));
typedef float    f32x4 __attribute__((ext_vector_type(4)));

#define DEVI __device__ __forceinline__

constexpr int BB = 2048;           // batch
constexpr int TT = 64;             // time steps
constexpr int II = 128;            // input size
constexpr int HH = 1024;           // hidden size
constexpr int BH = BB * HH;        // elements in one [B,H] state

DEVI void gload_lds16(const _Float16* g, _Float16* l) {
  // async global->LDS, 16B per lane; LDS dest is wave-uniform base + lane*16
  __builtin_amdgcn_global_load_lds(
      (const __attribute__((address_space(1))) void*)g,
      (__attribute__((address_space(3))) void*)l, 16, 0, 0);
}

DEVI float fsig(float x)  { return 1.0f / (1.0f + __expf(-x)); }
DEVI float ftanh(float x) { float e = __expf(2.0f * x); return 1.0f - 2.0f / (e + 1.0f); }

// ---------------------------------------------------------------------------
// GEMM core: C[128m x 128n] += A[128 x K] * B^T where B is [N][K] row-major.
// K is split in two source segments (seg0: kt < ktSplit, seg1: rest), each a
// separate (ptr, ld) pair -- used to fuse x@Wih + h@Whh in one K loop.
// GATES=true: tile col c -> weight row ((c>>4)&3)*H + n0 + (c>>6)*16 + (c&15)
// GATES=false: tile col c -> weight row n0 + c (plain GEMM, used for fc).
// LDS tiles are panel-major [4][128][8] halves: staging writes linearly
// (idx*16B), frag reads are 256B-contiguous per 16 lanes (conflict-free).
// ---------------------------------------------------------------------------
template<bool GATES>
DEVI void gemm_core(f32x4 acc[4][4],
    const _Float16* __restrict__ A0, int lda0,
    const _Float16* __restrict__ A1, int lda1,
    const _Float16* __restrict__ B0, int ldb0,
    const _Float16* __restrict__ B1, int ldb1,
    int ktSplit, int ktTotal, int m0, int n0,
    _Float16* sA0, _Float16* sA1, _Float16* sB0, _Float16* sB1,
    int tid, int wm, int wn, int lr, int lk)
{
  const _Float16* aS0[2]; const _Float16* aS1[2];
  const _Float16* bS0[2]; const _Float16* bS1[2];
#pragma unroll
  for (int i = 0; i < 2; ++i) {
    int idx = i * 256 + tid;
    int p = idx >> 7;        // k-panel 0..3 (8 halves each)
    int r = idx & 127;       // tile row (A: m-row, B: out-col)
    aS0[i] = A0 + (size_t)(m0 + r) * lda0 + p * 8;
    aS1[i] = A1 + (size_t)(m0 + r) * lda1 + p * 8;
    int br = GATES ? (((r >> 4) & 3) * HH + n0 + ((r >> 6) << 4) + (r & 15))
                   : (n0 + r);
    bS0[i] = B0 + (size_t)br * ldb0 + p * 8;
    bS1[i] = B1 + (size_t)br * ldb1 + p * 8;
  }

  auto stage = [&](_Float16* tA, _Float16* tB, int kt) {
    bool s0 = kt < ktSplit;
    int ko = (s0 ? kt : kt - ktSplit) * 32;
#pragma unroll
    for (int i = 0; i < 2; ++i) {
      gload_lds16((s0 ? aS0[i] : aS1[i]) + ko, tA + i * 2048 + tid * 8);
      gload_lds16((s0 ? bS0[i] : bS1[i]) + ko, tB + i * 2048 + tid * 8);
    }
  };

  const int aOff = lk * 1024 + (wm * 64 + lr) * 8;
  const int bOff = lk * 1024 + (wn * 64 + lr) * 8;

  auto compute = [&](const _Float16* tA, const _Float16* tB) {
    f16x8 av[4], bv[4];
#pragma unroll
    for (int q = 0; q < 4; ++q) av[q] = *(const f16x8*)(tA + aOff + q * 128);
#pragma unroll
    for (int q = 0; q < 4; ++q) bv[q] = *(const f16x8*)(tB + bOff + q * 128);
#pragma unroll
    for (int i = 0; i < 4; ++i)
#pragma unroll
      for (int j = 0; j < 4; ++j)
        acc[i][j] = __builtin_amdgcn_mfma_f32_16x16x32_f16(av[i], bv[j], acc[i][j], 0, 0, 0);
  };

  stage(sA0, sB0, 0);
  __syncthreads();
  for (int kt = 0; kt < ktTotal; kt += 2) {          // ktTotal is always even
    if (kt + 1 < ktTotal) stage(sA1, sB1, kt + 1);
    compute(sA0, sB0);
    __syncthreads();
    if (kt + 2 < ktTotal) stage(sA0, sB0, kt + 2);
    compute(sA1, sB1);
    __syncthreads();
  }
}

// ---------------------------------------------------------------------------
// blocks [0, ncell): LSTM cell tile (gate-fused). blocks [ncell, ...): fc GEMM
// for the PREVIOUS step's h2 (reads only, no dependency on this launch).
// ---------------------------------------------------------------------------
__global__ __launch_bounds__(256)
void lstm_gemm(
    const _Float16* __restrict__ A0, int lda0,
    const _Float16* __restrict__ A1, int lda1,
    const _Float16* __restrict__ B0, int ldb0,
    const _Float16* __restrict__ B1, int ldb1,
    int ktSplit, int ktTotal,
    const float* __restrict__ biasCell,   // [4H] = b_ih + b_hh
    float* __restrict__ cbuf,             // [B,H] fp32 running cell state
    _Float16* __restrict__ hout,          // [B,H] fp16 new hidden
    float* __restrict__ hF32,             // last step only (else null)
    float* __restrict__ cF32,             // last step only (else null)
    const _Float16* __restrict__ fcA,     // fc: h2 of previous step
    const _Float16* __restrict__ fcW,     // fc: [I,H] fp16 weights
    const float* __restrict__ fcBias,     // fc: [I]
    float* __restrict__ yout,             // fc: d_out + t_prev*I (null -> skip)
    int ncell)
{
  __shared__ __align__(16) _Float16 sA[2][4096];
  __shared__ __align__(16) _Float16 sB[2][4096];

  const int tid  = threadIdx.x;
  const int lane = tid & 63;
  const int wid  = tid >> 6;
  const int wm = wid >> 1, wn = wid & 1;   // 2x2 wave grid, wave tile 64x64
  const int lr = lane & 15, lk = lane >> 4;

  const f32x4 vzero = {0.f, 0.f, 0.f, 0.f};
  f32x4 acc[4][4];
#pragma unroll
  for (int i = 0; i < 4; ++i)
#pragma unroll
    for (int j = 0; j < 4; ++j) acc[i][j] = vzero;

  if ((int)blockIdx.x < ncell) {
    // -------------------- LSTM cell tile --------------------
    const int mt = blockIdx.x & 15;          // 16 m-tiles  (M=2048)
    const int nt = blockIdx.x >> 4;          // 32 unit-tiles (H=1024 / 32)
    const int m0 = mt * 128, u0 = nt * 32;
    gemm_core<true>(acc, A0, lda0, A1, lda1, B0, ldb0, B1, ldb1,
                    ktSplit, ktTotal, m0, u0,
                    sA[0], sA[1], sB[0], sB[1], tid, wm, wn, lr, lk);

    const int u = u0 + wn * 16 + lr;         // this lane's hidden unit
    const float bi = biasCell[u];
    const float bf = biasCell[HH + u];
    const float bg = biasCell[2 * HH + u];
    const float bo = biasCell[3 * HH + u];
#pragma unroll
    for (int mf = 0; mf < 4; ++mf) {
#pragma unroll
      for (int rg = 0; rg < 4; ++rg) {
        const int m = m0 + wm * 64 + mf * 16 + lk * 4 + rg;
        const size_t off = (size_t)m * HH + u;
        float iv = fsig (acc[mf][0][rg] + bi);
        float fv = fsig (acc[mf][1][rg] + bf);
        float gv = ftanh(acc[mf][2][rg] + bg);
        float ov = fsig (acc[mf][3][rg] + bo);
        float cn = fv * cbuf[off] + iv * gv;
        float hn = ov * ftanh(cn);
        cbuf[off] = cn;
        hout[off] = (_Float16)hn;
        if (hF32) { hF32[off] = hn; cF32[off] = cn; }
      }
    }
  } else {
    // -------------------- fc tile (previous step's h2) --------------------
    if (yout == nullptr) return;             // t==0: nothing to do yet
    const int m0 = ((int)blockIdx.x - ncell) * 128;
    gemm_core<false>(acc, fcA, HH, fcA, HH, fcW, HH, fcW, HH,
                     32, 32, m0, 0,
                     sA[0], sA[1], sB[0], sB[1], tid, wm, wn, lr, lk);
#pragma unroll
    for (int mf = 0; mf < 4; ++mf) {
#pragma unroll
      for (int fn = 0; fn < 4; ++fn) {
        const int col = wn * 64 + fn * 16 + lr;
        const float bb = fcBias[col];
#pragma unroll
        for (int rg = 0; rg < 4; ++rg) {
          const int m = m0 + wm * 64 + mf * 16 + lk * 4 + rg;
          yout[(size_t)m * (TT * II) + col] = acc[mf][fn][rg] + bb;
        }
      }
    }
  }
}

// ---------------------------------------------------------------------------
// prologue helpers
// ---------------------------------------------------------------------------
__global__ void cvt_f32_f16(const float* __restrict__ in,
                            _Float16* __restrict__ out, int n4) {
  int i  = blockIdx.x * blockDim.x + threadIdx.x;
  int st = gridDim.x * blockDim.x;
  for (; i < n4; i += st) {
    float4 v = ((const float4*)in)[i];
    f16x4 h;
    h[0] = (_Float16)v.x; h[1] = (_Float16)v.y;
    h[2] = (_Float16)v.z; h[3] = (_Float16)v.w;
    ((f16x4*)out)[i] = h;
  }
}

__global__ void bias_sum(const float* __restrict__ a, const float* __restrict__ b,
                         float* __restrict__ o, int n) {
  int i = blockIdx.x * blockDim.x + threadIdx.x;
  if (i < n) o[i] = a[i] + b[i];
}

// ---------------------------------------------------------------------------
extern "C" void kernel_launch(void* const* d_in, const int* in_sizes, int n_in,
                              void* d_out, int out_size, void* d_ws, size_t ws_size,
                              hipStream_t stream) {
  const float* x    = (const float*)d_in[0];
  const float* h1_0 = (const float*)d_in[1];
  const float* c1_0 = (const float*)d_in[2];
  const float* h2_0 = (const float*)d_in[3];
  const float* c2_0 = (const float*)d_in[4];
  const float* wih1 = (const float*)d_in[5];
  const float* whh1 = (const float*)d_in[6];
  const float* bih1 = (const float*)d_in[7];
  const float* bhh1 = (const float*)d_in[8];
  const float* wih2 = (const float*)d_in[9];
  const float* whh2 = (const float*)d_in[10];
  const float* bih2 = (const float*)d_in[11];
  const float* bhh2 = (const float*)d_in[12];
  const float* fcw  = (const float*)d_in[13];
  const float* fcb  = (const float*)d_in[14];
  float* out = (float*)d_out;

  // ---- workspace carve-out (~90 MB) ----
  char* p = (char*)d_ws;
  auto take = [&](size_t bytes) -> void* {
    void* r = (void*)p;
    p += (bytes + 511) & ~(size_t)511;
    return r;
  };
  _Float16* xh    = (_Float16*)take((size_t)BB * TT * II * 2);  // x in fp16
  _Float16* wih1h = (_Float16*)take((size_t)4096 * 128 * 2);
  _Float16* whh1h = (_Float16*)take((size_t)4096 * 1024 * 2);
  _Float16* wih2h = (_Float16*)take((size_t)4096 * 1024 * 2);
  _Float16* whh2h = (_Float16*)take((size_t)4096 * 1024 * 2);
  _Float16* fcwh  = (_Float16*)take((size_t)128 * 1024 * 2);
  float*    b1s   = (float*)take(4096 * 4);
  float*    b2s   = (float*)take(4096 * 4);
  _Float16* h1p   = (_Float16*)take((size_t)2 * BH * 2);        // ping-pong
  _Float16* h2p   = (_Float16*)take((size_t)2 * BH * 2);        // ping-pong
  float*    c1b   = (float*)take((size_t)BH * 4);
  float*    c2b   = (float*)take((size_t)BH * 4);

  // ---- prologue: fp16 conversions, bias sums, state init ----
  cvt_f32_f16<<<1024, 256, 0, stream>>>(x,    xh,    BB * TT * II / 4);
  cvt_f32_f16<<<256,  256, 0, stream>>>(wih1, wih1h, 4096 * 128 / 4);
  cvt_f32_f16<<<1024, 256, 0, stream>>>(whh1, whh1h, 4096 * 1024 / 4);
  cvt_f32_f16<<<1024, 256, 0, stream>>>(wih2, wih2h, 4096 * 1024 / 4);
  cvt_f32_f16<<<1024, 256, 0, stream>>>(whh2, whh2h, 4096 * 1024 / 4);
  cvt_f32_f16<<<128,  256, 0, stream>>>(fcw,  fcwh,  128 * 1024 / 4);
  cvt_f32_f16<<<512,  256, 0, stream>>>(h1_0, h1p + BH, BH / 4);  // slot 1
  cvt_f32_f16<<<512,  256, 0, stream>>>(h2_0, h2p + BH, BH / 4);  // slot 1
  bias_sum<<<16, 256, 0, stream>>>(bih1, bhh1, b1s, 4096);
  bias_sum<<<16, 256, 0, stream>>>(bih2, bhh2, b2s, 4096);
  hipMemcpyAsync(c1b, c1_0, (size_t)BH * 4, hipMemcpyDeviceToDevice, stream);
  hipMemcpyAsync(c2b, c2_0, (size_t)BH * 4, hipMemcpyDeviceToDevice, stream);

  // output layout: y [B,T,I], then h1, c1, h2, c2 (each [B,H])
  const size_t Oh1 = (size_t)BB * TT * II;
  const size_t Oc1 = Oh1 + BH;
  const size_t Oh2 = Oc1 + BH;
  const size_t Oc2 = Oh2 + BH;

  for (int t = 0; t < TT; ++t) {
    const bool last = (t == TT - 1);
    _Float16* h1r = h1p + (size_t)((t + 1) & 1) * BH;   // h1_{t-1}
    _Float16* h1w = h1p + (size_t)(t & 1) * BH;         // h1_t
    _Float16* h2r = h2p + (size_t)((t + 1) & 1) * BH;   // h2_{t-1}
    _Float16* h2w = h2p + (size_t)(t & 1) * BH;         // h2_t

    // cell1: gates = x_t @ Wih1^T + h1_{t-1} @ Whh1^T   (K = 128 + 1024)
    lstm_gemm<<<512, 256, 0, stream>>>(
        xh + (size_t)t * II, TT * II, h1r, HH,
        wih1h, II, whh1h, HH,
        4, 36, b1s, c1b, h1w,
        last ? out + Oh1 : nullptr, last ? out + Oc1 : nullptr,
        nullptr, nullptr, nullptr, nullptr, 512);

    // cell2 (+ fc of step t-1 riding on 16 extra blocks)
    lstm_gemm<<<528, 256, 0, stream>>>(
        h1w, HH, h2r, HH,
        wih2h, HH, whh2h, HH,
        32, 64, b2s, c2b, h2w,
        last ? out + Oh2 : nullptr, last ? out + Oc2 : nullptr,
        h2r, fcwh, fcb,
        (t > 0) ? out + (size_t)(t - 1) * II : nullptr, 512);
  }

  // final fc: y_{T-1} from h2_{T-1} (slot (T-1)&1 = 1)
  lstm_gemm<<<16, 256, 0, stream>>>(
      nullptr, 0, nullptr, 0, nullptr, 0, nullptr, 0,
      0, 0, nullptr, nullptr, nullptr, nullptr, nullptr,
      h2p + BH, fcwh, fcb, out + (size_t)(TT - 1) * II, 0);

  (void)in_sizes; (void)n_in; (void)out_size; (void)ws_size;
}